// Round 3
// baseline (770.610 us; speedup 1.0000x reference)
//
#include <hip/hip_runtime.h>
#include <hip/hip_fp16.h>

typedef unsigned int u32;
typedef unsigned short u16;
typedef u32 __attribute__((may_alias)) u32a;
typedef u16 __attribute__((may_alias)) u16a;
typedef uint4 __attribute__((may_alias)) uint4a;
typedef uint2 __attribute__((may_alias)) uint2a;
typedef float __attribute__((may_alias)) f32a;
typedef float4 __attribute__((may_alias)) float4a;

typedef __attribute__((ext_vector_type(8))) short short8v;  // 8 bf16 (4 VGPRs)
typedef __attribute__((ext_vector_type(4))) float float4v;  // 4 f32 acc

union Frag { uint4 q; short8v s; u16 u[8]; };
union F4 { float4 v; float f[4]; };

#define BATCH 16
#define CIN   512
#define NPIX  4096
#define DD    64
#define VV    256
#define MM    1024

__device__ __forceinline__ float b2f(u16 u) {
  union { u32 i; float f; } v; v.i = ((u32)u) << 16; return v.f;
}
__device__ __forceinline__ u16 f2b(float f) {
  union { float f; u32 i; } v; v.f = f;
  u32 u = v.i;
  u32 r = (u + 0x7fffu + ((u >> 16) & 1u)) >> 16;
  return (u16)r;
}
__device__ __forceinline__ u16 f2h(float f) { return __half_as_ushort(__float2half(f)); }
__device__ __forceinline__ float h2f(u16 u) { return __half2float(__ushort_as_half(u)); }

// packed RNE f32x2 -> bf16x2 (hardware cvt; same rounding as f2b)
__device__ __forceinline__ u32 cvtpk(float lo, float hi) {
  u32 r;
  asm("v_cvt_pk_bf16_f32 %0, %1, %2" : "=v"(r) : "v"(lo), "v"(hi));
  return r;
}

// packed bf16x2 dot product, f32 accumulate
__device__ __forceinline__ float dot2(u32 a, u32 b, float c) {
  union { u32 i; float f; } a0, a1, b0, b1;
  a0.i = a << 16; a1.i = a & 0xffff0000u;
  b0.i = b << 16; b1.i = b & 0xffff0000u;
  return fmaf(a1.f, b1.f, fmaf(a0.f, b0.f, c));
}

// ---------------------------------------------------------------------------
// K0a: input-dtype detection. meta[0] = 1 (inputs fp32) or 0 (inputs bf16).
// ---------------------------------------------------------------------------
__global__ __launch_bounds__(256) void k_detect(const void* __restrict__ x,
                                                u32* __restrict__ meta) {
  __shared__ int bad[256];
  const int t = threadIdx.x;
  float f = b2f(((const u16a*)x)[2 * t]);
  float a = fabsf(f);
  bad[t] = (a >= 1e-6f && a <= 100.f) ? 0 : 1;  // NaN -> bad (compares false)
  __syncthreads();
  if (t == 0) {
    int s = 0;
#pragma unroll 16
    for (int i = 0; i < 256; ++i) s += bad[i];
    meta[0] = (s > 64) ? 1u : 0u;
  }
}

// ---------------------------------------------------------------------------
// K0b: weights (+gamma) -> bf16 copy in ws.  wbf layout: wt@0, wp@32768,
// wg@65536, wo@196608 (u16 elements).  grid = 1280 x 256.
// ---------------------------------------------------------------------------
__global__ __launch_bounds__(256) void k_cvt(
    const void* __restrict__ wt, const void* __restrict__ wp,
    const void* __restrict__ wg, const void* __restrict__ wo,
    const void* __restrict__ gm, const u32* __restrict__ meta,
    u16* __restrict__ wbf, float* __restrict__ gout) {
  const int flag = (int)meta[0];
  const int i = blockIdx.x * 256 + threadIdx.x;
  const void* src; int j;
  if (i < 32768)       { src = wt; j = i; }
  else if (i < 65536)  { src = wp; j = i - 32768; }
  else if (i < 196608) { src = wg; j = i - 65536; }
  else                 { src = wo; j = i - 196608; }
  wbf[i] = flag ? f2b(((const f32a*)src)[j]) : ((const u16a*)src)[j];
  if (i == 0)
    gout[0] = flag ? ((const f32a*)gm)[0] : b2f(((const u16a*)gm)[0]);
}

// ---------------------------------------------------------------------------
// K1 (MFMA): theta/phi/g projections + fused 2x2 maxpool for phi,g.
// grid = 16 b * 32 pxt (128 px = 2 image rows each), 256 threads (4 waves).
// ---------------------------------------------------------------------------
__global__ __launch_bounds__(256) void k_proj(
    const void* __restrict__ x, const u16* __restrict__ w_all,
    const u32* __restrict__ meta,
    u16* __restrict__ theta, u16* __restrict__ phi_t, u16* __restrict__ g)
{
  __shared__ __align__(16) u16 xs[128][136];
  const int tid  = threadIdx.x;
  const int lane = tid & 63;
  const int wv   = tid >> 6;
  const int lg   = lane >> 4;      // k-group 0..3
  const int lr   = lane & 15;      // row/col within fragment
  const int blk  = blockIdx.x;
  const int b    = blk >> 5;
  const int pxt  = blk & 31;
  const int n0   = pxt * 128;      // 2 image rows y0=2*pxt, y0+1
  const int rbase = wv * 96;
  const int flag = (int)meta[0];

  float4v acc[6][8];
#pragma unroll
  for (int i = 0; i < 6; ++i)
#pragma unroll
    for (int j = 0; j < 8; ++j) acc[i][j] = (float4v){0.f, 0.f, 0.f, 0.f};

  const int pg = tid & 15;         // px quad: [pg*4, pg*4+4) and +64
  const int cg = tid >> 4;         // channel octet: [cg*8, cg*8+8)

  for (int cc = 0; cc < 4; ++cc) {
    const int c0 = cc * 128;
    __syncthreads();
    if (flag) {
      const f32a* src = (const f32a*)x +
          ((size_t)(b * CIN + c0 + cg * 8)) * NPIX + n0 + pg * 4;
#pragma unroll
      for (int cq = 0; cq < 2; ++cq) {        // two channel-quads
        const f32a* s4 = src + (size_t)(cq * 4) * NPIX;
        F4 a0, a1, a2, a3, b0, b1, b2, b3;
        a0.v = *(const float4a*)(s4);
        b0.v = *(const float4a*)(s4 + 64);
        a1.v = *(const float4a*)(s4 + NPIX);
        b1.v = *(const float4a*)(s4 + NPIX + 64);
        a2.v = *(const float4a*)(s4 + 2 * (size_t)NPIX);
        b2.v = *(const float4a*)(s4 + 2 * (size_t)NPIX + 64);
        a3.v = *(const float4a*)(s4 + 3 * (size_t)NPIX);
        b3.v = *(const float4a*)(s4 + 3 * (size_t)NPIX + 64);
        const int colb = cg * 8 + cq * 4;
#pragma unroll
        for (int j = 0; j < 4; ++j) {
          uint2 wd; wd.x = cvtpk(a0.f[j], a1.f[j]); wd.y = cvtpk(a2.f[j], a3.f[j]);
          *(uint2a*)&xs[pg * 4 + j][colb] = wd;
          uint2 vd; vd.x = cvtpk(b0.f[j], b1.f[j]); vd.y = cvtpk(b2.f[j], b3.f[j]);
          *(uint2a*)&xs[64 + pg * 4 + j][colb] = vd;
        }
      }
    } else {
#pragma unroll 8
      for (int it = 0; it < 64; ++it) {
        int idx = tid + it * 256;
        int cl = idx >> 7, px = idx & 127;
        xs[px][cl] = ((const u16a*)x)[((size_t)(b * CIN + c0 + cl)) * NPIX + (n0 + px)];
      }
    }
    __syncthreads();

#pragma unroll
    for (int kk = 0; kk < 4; ++kk) {
      short8v bfr[8];
#pragma unroll
      for (int pt = 0; pt < 8; ++pt) {
        Frag f; f.q = *(const uint4a*)&xs[pt * 16 + lr][kk * 32 + lg * 8];
        bfr[pt] = f.s;
      }
#pragma unroll
      for (int rt = 0; rt < 6; ++rt) {
        Frag af;
        af.q = *(const uint4a*)(w_all +
            (size_t)(rbase + rt * 16 + lr) * CIN + c0 + kk * 32 + lg * 8);
#pragma unroll
        for (int pt = 0; pt < 8; ++pt)
          acc[rt][pt] = __builtin_amdgcn_mfma_f32_16x16x32_bf16(af.s, bfr[pt], acc[rt][pt], 0, 0, 0);
      }
    }
  }

#pragma unroll
  for (int rt = 0; rt < 6; ++rt) {
    const int rowb = rbase + rt * 16;
    if (rowb < 64) {
#pragma unroll
      for (int pt = 0; pt < 8; ++pt)
#pragma unroll
        for (int r = 0; r < 4; ++r) {
          int row = rowb + lg * 4 + r;
          theta[((size_t)(b * DD + row)) * NPIX + n0 + pt * 16 + lr] = f2b(acc[rt][pt][r]);
        }
    } else {
#pragma unroll
      for (int pt = 0; pt < 4; ++pt)
#pragma unroll
        for (int r = 0; r < 4; ++r) {
          int row = rowb + lg * 4 + r;
          float pm = fmaxf(acc[rt][pt][r], acc[rt][pt + 4][r]);
          float po = fmaxf(pm, __shfl_xor(pm, 1));
          if (!(lr & 1)) {
            int m = pxt * 32 + pt * 8 + (lr >> 1);
            if (row < 128) phi_t[((size_t)(b * MM + m)) * DD + (row - 64)] = f2b(po);
            else           g[((size_t)(b * VV + (row - 128))) * MM + m]    = f2b(po);
          }
        }
    }
  }
}

// ---------------------------------------------------------------------------
// K2a (split path): attention core only -> o_t[b][n][v] bf16.
// grid = 4096 (16 b * 256 qtiles), XCD-swizzled so each XCD owns 2 batches
// (phi+g stay L2-resident). LDS 34.4 KB -> 4 blocks/CU.
// pass1 computes per-wave softmax max in-register (C frag row=q, col=m).
// pass3 is 2-deep pipelined on the g/P fragment loads.
// ---------------------------------------------------------------------------
__global__ __launch_bounds__(256) void k_attn2(
    const u16* __restrict__ theta, const u16* __restrict__ phi_t,
    const u16* __restrict__ g, u16* __restrict__ o_t)
{
  __shared__ __align__(16) u32 sc[16 * 516];   // fp16 scores -> exp'd bf16 pairs
  __shared__ float pmax4[16][4];
  __shared__ float psum[16][16];
  __shared__ float sinv_s[16];

  const int tid  = threadIdx.x;
  const int lane = tid & 63;
  const int wv   = tid >> 6;       // wave id 0..3
  const int lg   = lane >> 4;      // lane-group 0..3 (k dimension)
  const int lr   = lane & 15;      // row/col within fragment
  const int bid  = blockIdx.x;
  const int swz  = ((bid & 7) << 9) | (bid >> 3);   // 4096 blocks, 8 XCDs
  const int b    = swz >> 8;
  const int qt   = swz & 255;
  const int nq0  = qt * 16;

  u16a* sc16 = (u16a*)sc;

  // ---- Q fragments (A operand) ----
  short8v qa[2];
#pragma unroll
  for (int kk = 0; kk < 2; ++kk) {
    Frag f;
#pragma unroll
    for (int i = 0; i < 8; ++i) {
      int d = kk * 32 + lg * 8 + i;
      f.u[i] = theta[((size_t)(b * DD + d)) * NPIX + nq0 + lr];
    }
    qa[kk] = f.s;
  }

  // ---- pass 1: scores + in-register per-wave max; wave owns m in [wv*256,+256) ----
  float mxq[4] = {-3.0e38f, -3.0e38f, -3.0e38f, -3.0e38f};
  {
    const u16* pt = phi_t + (size_t)b * (MM * DD);
#pragma unroll 2
    for (int mt = 0; mt < 16; ++mt) {
      const int m0 = wv * 256 + mt * 16;
      float4v s = {0.f, 0.f, 0.f, 0.f};
#pragma unroll
      for (int kk = 0; kk < 2; ++kk) {
        Frag f; f.q = *(const uint4a*)(pt + (size_t)(m0 + lr) * DD + kk * 32 + lg * 8);
        s = __builtin_amdgcn_mfma_f32_16x16x32_bf16(qa[kk], f.s, s, 0, 0, 0);
      }
#pragma unroll
      for (int r = 0; r < 4; ++r) {
        float v = fminf(fmaxf(s[r], -6.0e4f), 6.0e4f);  // fp16-safe clamp
        sc16[(lg * 4 + r) * 1032 + m0 + lr] = f2h(v);
        mxq[r] = fmaxf(mxq[r], v);
      }
    }
    // reduce max over the 16 lr lanes (same q set within each lg group)
#pragma unroll
    for (int m = 1; m < 16; m <<= 1)
#pragma unroll
      for (int r = 0; r < 4; ++r) mxq[r] = fmaxf(mxq[r], __shfl_xor(mxq[r], m));
    if (lr == 0) {
#pragma unroll
      for (int r = 0; r < 4; ++r) pmax4[lg * 4 + r][wv] = mxq[r];
    }
  }
  __syncthreads();

  // ---- pass 2: exp + sum; in-place repack to bf16 pairs ----
  const int q  = tid & 15;
  const int sg = tid >> 4;    // 16 segments x 64 m
  {
    float maxq = fmaxf(fmaxf(pmax4[q][0], pmax4[q][1]),
                       fmaxf(pmax4[q][2], pmax4[q][3]));
    float ssum = 0.f;
#pragma unroll 4
    for (int kp = 0; kp < 32; ++kp) {
      int kk = (kp + sg) & 31;
      int idx = q * 516 + sg * 32 + kk;
      u32 raw = sc[idx];
      float f0 = h2f((u16)(raw & 0xffffu));
      float f1 = h2f((u16)(raw >> 16));
      float e0 = __expf(fminf(f0 - maxq, 0.f));
      float e1 = __expf(fminf(f1 - maxq, 0.f));
      ssum += e0 + e1;
      sc[idx] = (u32)f2b(e0) | ((u32)f2b(e1) << 16);
    }
    psum[q][sg] = ssum;
    __syncthreads();
    float tot = 0.f;
#pragma unroll
    for (int i = 0; i < 16; ++i) tot += psum[q][i];
    if (sg == 0) sinv_s[q] = 1.f / tot;
  }
  __syncthreads();

  // ---- pass 3: o[v][q] = sum_m g[v][m] P[q][m]; wave owns v in [wv*64,+64) ----
  {
    float4v oacc[4];
#pragma unroll
    for (int i = 0; i < 4; ++i) oacc[i] = (float4v){0.f, 0.f, 0.f, 0.f};
    const u16* gb = g + (size_t)b * (VV * MM) + (size_t)(wv * 64 + lr) * MM + lg * 8;

    Frag pf; uint4 gq[4];
    pf.q = *(const uint4a*)(sc16 + lr * 1032 + lg * 8);
#pragma unroll
    for (int vt = 0; vt < 4; ++vt) gq[vt] = *(const uint4a*)(gb + (size_t)vt * 16 * MM);

#pragma unroll 4
    for (int ms = 0; ms < 32; ++ms) {
      Frag pfn = pf; uint4 gn[4] = {gq[0], gq[1], gq[2], gq[3]};
      if (ms < 31) {
        pfn.q = *(const uint4a*)(sc16 + lr * 1032 + (ms + 1) * 32 + lg * 8);
#pragma unroll
        for (int vt = 0; vt < 4; ++vt)
          gn[vt] = *(const uint4a*)(gb + (size_t)vt * 16 * MM + (ms + 1) * 32);
      }
#pragma unroll
      for (int vt = 0; vt < 4; ++vt) {
        Frag gf; gf.q = gq[vt];
        oacc[vt] = __builtin_amdgcn_mfma_f32_16x16x32_bf16(gf.s, pf.s, oacc[vt], 0, 0, 0);
      }
      pf = pfn;
#pragma unroll
      for (int vt = 0; vt < 4; ++vt) gq[vt] = gn[vt];
    }

    const float si = sinv_s[lr];   // softmax denominator for this q column
#pragma unroll
    for (int vt = 0; vt < 4; ++vt) {
      uint2 wd;
      wd.x = cvtpk(oacc[vt][0] * si, oacc[vt][1] * si);
      wd.y = cvtpk(oacc[vt][2] * si, oacc[vt][3] * si);
      *(uint2a*)(o_t + ((size_t)(b * NPIX + nq0 + lr)) * VV + wv * 64 + vt * 16 + lg * 4) = wd;
    }
  }
}

// ---------------------------------------------------------------------------
// K2b (split path): out = gamma * (wo . o) + x.  GEMM over [512 oc][64 n]
// tiles, K = 256 v.  grid = 1024 (16 b * 64 ntiles), XCD-swizzled.
// ---------------------------------------------------------------------------
__global__ __launch_bounds__(256) void k_oproj(
    const u16* __restrict__ o_t, const u16* __restrict__ wo,
    const void* __restrict__ x, const float* __restrict__ gamma_p,
    const u32* __restrict__ meta, void* __restrict__ out)
{
  __shared__ __align__(16) u16 os[64][264];
  const int tid  = threadIdx.x;
  const int lane = tid & 63;
  const int wv   = tid >> 6;
  const int lg   = lane >> 4;
  const int lr   = lane & 15;
  const int bid  = blockIdx.x;
  const int swz  = ((bid & 7) << 7) | (bid >> 3);   // 1024 blocks, 8 XCDs
  const int b    = swz >> 6;
  const int nt   = swz & 63;
  const int n0   = nt * 64;
  const int flag = (int)meta[0];

  // stage o tile [64 n][256 v], coalesced uint4 rows
#pragma unroll
  for (int it = 0; it < 8; ++it) {
    int idx = tid + it * 256;
    int row = idx >> 5, cq = idx & 31;
    *(uint4a*)&os[row][cq * 8] =
        *(const uint4a*)(o_t + ((size_t)(b * NPIX + n0 + row)) * VV + cq * 8);
  }
  __syncthreads();

  float4v acc[8][4];
#pragma unroll
  for (int i = 0; i < 8; ++i)
#pragma unroll
    for (int j = 0; j < 4; ++j) acc[i][j] = (float4v){0.f, 0.f, 0.f, 0.f};

#pragma unroll
  for (int kk = 0; kk < 8; ++kk) {
    short8v bf4[4];
#pragma unroll
    for (int pt = 0; pt < 4; ++pt) {
      Frag f; f.q = *(const uint4a*)&os[pt * 16 + lr][kk * 32 + lg * 8];
      bf4[pt] = f.s;
    }
#pragma unroll
    for (int rt = 0; rt < 8; ++rt) {
      Frag af;
      af.q = *(const uint4a*)(wo + (size_t)(wv * 128 + rt * 16 + lr) * VV + kk * 32 + lg * 8);
#pragma unroll
      for (int pt = 0; pt < 4; ++pt)
        acc[rt][pt] = __builtin_amdgcn_mfma_f32_16x16x32_bf16(af.s, bf4[pt], acc[rt][pt], 0, 0, 0);
    }
  }

  const float gmv = gamma_p[0];
#pragma unroll
  for (int rt = 0; rt < 8; ++rt) {
#pragma unroll
    for (int pt = 0; pt < 4; ++pt) {
#pragma unroll
      for (int r = 0; r < 4; ++r) {
        int oc = wv * 128 + rt * 16 + lg * 4 + r;
        size_t off = ((size_t)(b * CIN + oc)) * NPIX + n0 + pt * 16 + lr;
        if (flag) {
          ((f32a*)out)[off] = gmv * acc[rt][pt][r] + ((const f32a*)x)[off];
        } else {
          ((u16a*)out)[off] = f2b(gmv * acc[rt][pt][r] + b2f(((const u16a*)x)[off]));
        }
      }
    }
  }
}

// ---------------------------------------------------------------------------
// K2 (fused fallback, used only if workspace can't hold o_t): unchanged.
// ---------------------------------------------------------------------------
__global__ __launch_bounds__(256) void k_attn(
    const u16* __restrict__ theta, const u16* __restrict__ phi_t,
    const u16* __restrict__ g, const u16* __restrict__ wo,
    const void* __restrict__ x, const float* __restrict__ gamma_p,
    const u32* __restrict__ meta, void* __restrict__ out)
{
  __shared__ __align__(16) u32 sc[16 * 516];
  __shared__ __align__(16) u16 ot[16 * 264];
  __shared__ float pmax[16][16];
  __shared__ float psum[16][16];
  __shared__ float sinv_s[16];

  const int tid  = threadIdx.x;
  const int lane = tid & 63;
  const int wv   = tid >> 6;
  const int lg   = lane >> 4;
  const int lr   = lane & 15;
  const int blk  = blockIdx.x;
  const int b    = blk >> 8;
  const int qt   = blk & 255;
  const int nq0  = qt * 16;
  const int flag = (int)meta[0];

  u16a* sc16 = (u16a*)sc;

  short8v qa[2];
#pragma unroll
  for (int kk = 0; kk < 2; ++kk) {
    Frag f;
#pragma unroll
    for (int i = 0; i < 8; ++i) {
      int d = kk * 32 + lg * 8 + i;
      f.u[i] = theta[((size_t)(b * DD + d)) * NPIX + nq0 + lr];
    }
    qa[kk] = f.s;
  }

  {
    const u16* pt = phi_t + (size_t)b * (MM * DD);
#pragma unroll 2
    for (int mt = 0; mt < 16; ++mt) {
      const int m0 = wv * 256 + mt * 16;
      float4v s = {0.f, 0.f, 0.f, 0.f};
#pragma unroll
      for (int kk = 0; kk < 2; ++kk) {
        Frag f; f.q = *(const uint4a*)(pt + (size_t)(m0 + lr) * DD + kk * 32 + lg * 8);
        s = __builtin_amdgcn_mfma_f32_16x16x32_bf16(qa[kk], f.s, s, 0, 0, 0);
      }
#pragma unroll
      for (int r = 0; r < 4; ++r) {
        int qq = lg * 4 + r;
        float v = fminf(fmaxf(s[r], -6.0e4f), 6.0e4f);
        sc16[qq * 1032 + m0 + lr] = f2h(v);
      }
    }
  }
  __syncthreads();

  {
    const int q  = tid & 15;
    const int sg = tid >> 4;
    float mx = -3.0e38f;
#pragma unroll 8
    for (int k = 0; k < 64; ++k) {
      int kk = (k + sg * 2) & 63;
      mx = fmaxf(mx, h2f(sc16[q * 1032 + sg * 64 + kk]));
    }
    pmax[q][sg] = mx;
    __syncthreads();
    float maxq = -3.0e38f;
#pragma unroll
    for (int i = 0; i < 16; ++i) maxq = fmaxf(maxq, pmax[q][i]);
    float ssum = 0.f;
#pragma unroll 4
    for (int kp = 0; kp < 32; ++kp) {
      int kk = (kp + sg) & 31;
      int idx = q * 516 + sg * 32 + kk;
      u32 raw = sc[idx];
      float f0 = h2f((u16)(raw & 0xffffu));
      float f1 = h2f((u16)(raw >> 16));
      float e0 = __expf(fminf(f0 - maxq, 0.f));
      float e1 = __expf(fminf(f1 - maxq, 0.f));
      ssum += e0 + e1;
      sc[idx] = (u32)f2b(e0) | ((u32)f2b(e1) << 16);
    }
    psum[q][sg] = ssum;
    __syncthreads();
    float tot = 0.f;
#pragma unroll
    for (int i = 0; i < 16; ++i) tot += psum[q][i];
    if (sg == 0) sinv_s[q] = 1.f / tot;
  }
  __syncthreads();

  const int q  = tid & 15;
  const int sg = tid >> 4;
  {
    float4v oacc[4];
#pragma unroll
    for (int i = 0; i < 4; ++i) oacc[i] = (float4v){0.f, 0.f, 0.f, 0.f};
    const u16* gb = g + (size_t)b * (VV * MM);
#pragma unroll 2
    for (int ms = 0; ms < 32; ++ms) {
      Frag pf; pf.q = *(const uint4a*)(sc16 + lr * 1032 + ms * 32 + lg * 8);
#pragma unroll
      for (int vt = 0; vt < 4; ++vt) {
        Frag gf; gf.q = *(const uint4a*)(gb + (size_t)(wv * 64 + vt * 16 + lr) * MM + ms * 32 + lg * 8);
        oacc[vt] = __builtin_amdgcn_mfma_f32_16x16x32_bf16(gf.s, pf.s, oacc[vt], 0, 0, 0);
      }
    }
    const float si = sinv_s[lr];
#pragma unroll
    for (int vt = 0; vt < 4; ++vt) {
      u32 lo = (u32)f2b(oacc[vt][0] * si) | ((u32)f2b(oacc[vt][1] * si) << 16);
      u32 hi = (u32)f2b(oacc[vt][2] * si) | ((u32)f2b(oacc[vt][3] * si) << 16);
      u32a* p = (u32a*)&ot[lr * 264 + wv * 64 + vt * 16 + lg * 4];
      p[0] = lo; p[1] = hi;
    }
  }
  __syncthreads();

  {
    short8v ob[8];
#pragma unroll
    for (int ks = 0; ks < 8; ++ks) {
      Frag f; f.q = *(const uint4a*)(ot + lr * 264 + ks * 32 + lg * 8);
      ob[ks] = f.s;
    }
    const float gmv = gamma_p[0];
    const int oc0 = wv * 128;
#pragma unroll 2
    for (int oct = 0; oct < 8; ++oct) {
      float4v c = {0.f, 0.f, 0.f, 0.f};
#pragma unroll
      for (int ks = 0; ks < 8; ++ks) {
        Frag f; f.q = *(const uint4a*)(wo + (size_t)(oc0 + oct * 16 + lr) * VV + ks * 32 + lg * 8);
        c = __builtin_amdgcn_mfma_f32_16x16x32_bf16(f.s, ob[ks], c, 0, 0, 0);
      }
#pragma unroll
      for (int r = 0; r < 4; ++r) {
        int oc = oc0 + oct * 16 + lg * 4 + r;
        size_t off = ((size_t)(b * CIN + oc)) * NPIX + nq0 + lr;
        if (flag) {
          ((f32a*)out)[off] = gmv * c[r] + ((const f32a*)x)[off];
        } else {
          ((u16a*)out)[off] = f2b(gmv * c[r] + b2f(((const u16a*)x)[off]));
        }
      }
    }
  }
}

extern "C" void kernel_launch(void* const* d_in, const int* in_sizes, int n_in,
                              void* d_out, int out_size, void* d_ws, size_t ws_size,
                              hipStream_t stream) {
  (void)in_sizes; (void)n_in; (void)out_size;
  const void* x  = d_in[0];
  const void* wt = d_in[1];
  const void* wp = d_in[2];
  const void* wg = d_in[3];
  const void* wo = d_in[4];
  const void* gm = d_in[5];

  u16* theta = (u16*)d_ws;                              // [16][64][4096]  bf16
  u16* phi_t = theta + (size_t)BATCH * DD * NPIX;       // [16][1024][64]  bf16
  u16* g     = phi_t + (size_t)BATCH * MM * DD;         // [16][256][1024] bf16
  u16* wbf   = g     + (size_t)BATCH * VV * MM;         // 327680 bf16 weights
  float* gamma_f = (float*)(wbf + 327680);              // converted gamma
  u32* meta      = (u32*)(gamma_f + 1);                 // dtype flag
  u16* o_t   = (u16*)d_ws + 9764896;                    // [16][4096][256] bf16 (split path)
  const size_t need = ((size_t)9764896 + (size_t)BATCH * NPIX * VV) * 2;

  hipLaunchKernelGGL(k_detect, dim3(1), dim3(256), 0, stream, x, meta);
  hipLaunchKernelGGL(k_cvt, dim3(1280), dim3(256), 0, stream,
                     wt, wp, wg, wo, gm, meta, wbf, gamma_f);
  hipLaunchKernelGGL(k_proj, dim3(BATCH * 32), dim3(256), 0, stream,
                     x, wbf, meta, theta, phi_t, g);
  if (ws_size >= need) {
    hipLaunchKernelGGL(k_attn2, dim3(BATCH * 256), dim3(256), 0, stream,
                       theta, phi_t, g, o_t);
    hipLaunchKernelGGL(k_oproj, dim3(BATCH * 64), dim3(256), 0, stream,
                       o_t, wbf + 196608, x, gamma_f, meta, d_out);
  } else {
    hipLaunchKernelGGL(k_attn, dim3(BATCH * 256), dim3(256), 0, stream,
                       theta, phi_t, g, wbf + 196608, x, gamma_f, meta, d_out);
  }
}

// Round 4
// 636.915 us; speedup vs baseline: 1.2099x; 1.2099x over previous
//
#include <hip/hip_runtime.h>
#include <hip/hip_fp16.h>

typedef unsigned int u32;
typedef unsigned short u16;
typedef u32 __attribute__((may_alias)) u32a;
typedef u16 __attribute__((may_alias)) u16a;
typedef uint4 __attribute__((may_alias)) uint4a;
typedef uint2 __attribute__((may_alias)) uint2a;
typedef float __attribute__((may_alias)) f32a;
typedef float4 __attribute__((may_alias)) float4a;

typedef __attribute__((ext_vector_type(8))) short short8v;  // 8 bf16 (4 VGPRs)
typedef __attribute__((ext_vector_type(4))) float float4v;  // 4 f32 acc

union Frag { uint4 q; short8v s; u16 u[8]; };
union F4 { float4 v; float f[4]; };

#define BATCH 16
#define CIN   512
#define NPIX  4096
#define DD    64
#define VV    256
#define MM    1024

__device__ __forceinline__ float b2f(u16 u) {
  union { u32 i; float f; } v; v.i = ((u32)u) << 16; return v.f;
}
__device__ __forceinline__ u16 f2b(float f) {
  union { float f; u32 i; } v; v.f = f;
  u32 u = v.i;
  u32 r = (u + 0x7fffu + ((u >> 16) & 1u)) >> 16;
  return (u16)r;
}
__device__ __forceinline__ u16 f2h(float f) { return __half_as_ushort(__float2half(f)); }
__device__ __forceinline__ float h2f(u16 u) { return __half2float(__ushort_as_half(u)); }

// packed RNE f32x2 -> bf16x2 (hardware cvt; same rounding as f2b)
__device__ __forceinline__ u32 cvtpk(float lo, float hi) {
  u32 r;
  asm("v_cvt_pk_bf16_f32 %0, %1, %2" : "=v"(r) : "v"(lo), "v"(hi));
  return r;
}

// packed bf16x2 dot product, f32 accumulate
__device__ __forceinline__ float dot2(u32 a, u32 b, float c) {
  union { u32 i; float f; } a0, a1, b0, b1;
  a0.i = a << 16; a1.i = a & 0xffff0000u;
  b0.i = b << 16; b1.i = b & 0xffff0000u;
  return fmaf(a1.f, b1.f, fmaf(a0.f, b0.f, c));
}

// ---------------------------------------------------------------------------
// K0a: input-dtype detection. meta[0] = 1 (inputs fp32) or 0 (inputs bf16).
// ---------------------------------------------------------------------------
__global__ __launch_bounds__(256) void k_detect(const void* __restrict__ x,
                                                u32* __restrict__ meta) {
  __shared__ int bad[256];
  const int t = threadIdx.x;
  float f = b2f(((const u16a*)x)[2 * t]);
  float a = fabsf(f);
  bad[t] = (a >= 1e-6f && a <= 100.f) ? 0 : 1;  // NaN -> bad (compares false)
  __syncthreads();
  if (t == 0) {
    int s = 0;
#pragma unroll 16
    for (int i = 0; i < 256; ++i) s += bad[i];
    meta[0] = (s > 64) ? 1u : 0u;
  }
}

// ---------------------------------------------------------------------------
// K0b: weights (+gamma) -> bf16 copy in ws.  wbf layout: wt@0, wp@32768,
// wg@65536, wo@196608 (u16 elements).  grid = 1280 x 256.
// ---------------------------------------------------------------------------
__global__ __launch_bounds__(256) void k_cvt(
    const void* __restrict__ wt, const void* __restrict__ wp,
    const void* __restrict__ wg, const void* __restrict__ wo,
    const void* __restrict__ gm, const u32* __restrict__ meta,
    u16* __restrict__ wbf, float* __restrict__ gout) {
  const int flag = (int)meta[0];
  const int i = blockIdx.x * 256 + threadIdx.x;
  const void* src; int j;
  if (i < 32768)       { src = wt; j = i; }
  else if (i < 65536)  { src = wp; j = i - 32768; }
  else if (i < 196608) { src = wg; j = i - 65536; }
  else                 { src = wo; j = i - 196608; }
  wbf[i] = flag ? f2b(((const f32a*)src)[j]) : ((const u16a*)src)[j];
  if (i == 0)
    gout[0] = flag ? ((const f32a*)gm)[0] : b2f(((const u16a*)gm)[0]);
}

// ---------------------------------------------------------------------------
// K1 (MFMA): theta/phi/g projections + fused 2x2 maxpool for phi,g.
// grid = 16 b * 32 pxt (128 px = 2 image rows each), 256 threads (4 waves).
// ---------------------------------------------------------------------------
__global__ __launch_bounds__(256) void k_proj(
    const void* __restrict__ x, const u16* __restrict__ w_all,
    const u32* __restrict__ meta,
    u16* __restrict__ theta, u16* __restrict__ phi_t, u16* __restrict__ g)
{
  __shared__ __align__(16) u16 xs[128][136];
  const int tid  = threadIdx.x;
  const int lane = tid & 63;
  const int wv   = tid >> 6;
  const int lg   = lane >> 4;      // k-group 0..3
  const int lr   = lane & 15;      // row/col within fragment
  const int blk  = blockIdx.x;
  const int b    = blk >> 5;
  const int pxt  = blk & 31;
  const int n0   = pxt * 128;      // 2 image rows y0=2*pxt, y0+1
  const int rbase = wv * 96;
  const int flag = (int)meta[0];

  float4v acc[6][8];
#pragma unroll
  for (int i = 0; i < 6; ++i)
#pragma unroll
    for (int j = 0; j < 8; ++j) acc[i][j] = (float4v){0.f, 0.f, 0.f, 0.f};

  const int pg = tid & 15;         // px quad: [pg*4, pg*4+4) and +64
  const int cg = tid >> 4;         // channel octet: [cg*8, cg*8+8)

  for (int cc = 0; cc < 4; ++cc) {
    const int c0 = cc * 128;
    __syncthreads();
    if (flag) {
      const f32a* src = (const f32a*)x +
          ((size_t)(b * CIN + c0 + cg * 8)) * NPIX + n0 + pg * 4;
#pragma unroll
      for (int cq = 0; cq < 2; ++cq) {        // two channel-quads
        const f32a* s4 = src + (size_t)(cq * 4) * NPIX;
        F4 a0, a1, a2, a3, b0, b1, b2, b3;
        a0.v = *(const float4a*)(s4);
        b0.v = *(const float4a*)(s4 + 64);
        a1.v = *(const float4a*)(s4 + NPIX);
        b1.v = *(const float4a*)(s4 + NPIX + 64);
        a2.v = *(const float4a*)(s4 + 2 * (size_t)NPIX);
        b2.v = *(const float4a*)(s4 + 2 * (size_t)NPIX + 64);
        a3.v = *(const float4a*)(s4 + 3 * (size_t)NPIX);
        b3.v = *(const float4a*)(s4 + 3 * (size_t)NPIX + 64);
        const int colb = cg * 8 + cq * 4;
#pragma unroll
        for (int j = 0; j < 4; ++j) {
          uint2 wd; wd.x = cvtpk(a0.f[j], a1.f[j]); wd.y = cvtpk(a2.f[j], a3.f[j]);
          *(uint2a*)&xs[pg * 4 + j][colb] = wd;
          uint2 vd; vd.x = cvtpk(b0.f[j], b1.f[j]); vd.y = cvtpk(b2.f[j], b3.f[j]);
          *(uint2a*)&xs[64 + pg * 4 + j][colb] = vd;
        }
      }
    } else {
#pragma unroll 8
      for (int it = 0; it < 64; ++it) {
        int idx = tid + it * 256;
        int cl = idx >> 7, px = idx & 127;
        xs[px][cl] = ((const u16a*)x)[((size_t)(b * CIN + c0 + cl)) * NPIX + (n0 + px)];
      }
    }
    __syncthreads();

#pragma unroll
    for (int kk = 0; kk < 4; ++kk) {
      short8v bfr[8];
#pragma unroll
      for (int pt = 0; pt < 8; ++pt) {
        Frag f; f.q = *(const uint4a*)&xs[pt * 16 + lr][kk * 32 + lg * 8];
        bfr[pt] = f.s;
      }
#pragma unroll
      for (int rt = 0; rt < 6; ++rt) {
        Frag af;
        af.q = *(const uint4a*)(w_all +
            (size_t)(rbase + rt * 16 + lr) * CIN + c0 + kk * 32 + lg * 8);
#pragma unroll
        for (int pt = 0; pt < 8; ++pt)
          acc[rt][pt] = __builtin_amdgcn_mfma_f32_16x16x32_bf16(af.s, bfr[pt], acc[rt][pt], 0, 0, 0);
      }
    }
  }

#pragma unroll
  for (int rt = 0; rt < 6; ++rt) {
    const int rowb = rbase + rt * 16;
    if (rowb < 64) {
#pragma unroll
      for (int pt = 0; pt < 8; ++pt)
#pragma unroll
        for (int r = 0; r < 4; ++r) {
          int row = rowb + lg * 4 + r;
          theta[((size_t)(b * DD + row)) * NPIX + n0 + pt * 16 + lr] = f2b(acc[rt][pt][r]);
        }
    } else {
#pragma unroll
      for (int pt = 0; pt < 4; ++pt)
#pragma unroll
        for (int r = 0; r < 4; ++r) {
          int row = rowb + lg * 4 + r;
          float pm = fmaxf(acc[rt][pt][r], acc[rt][pt + 4][r]);
          float po = fmaxf(pm, __shfl_xor(pm, 1));
          if (!(lr & 1)) {
            int m = pxt * 32 + pt * 8 + (lr >> 1);
            if (row < 128) phi_t[((size_t)(b * MM + m)) * DD + (row - 64)] = f2b(po);
            else           g[((size_t)(b * VV + (row - 128))) * MM + m]    = f2b(po);
          }
        }
    }
  }
}

// ---------------------------------------------------------------------------
// K2a (split path, QBLK=32): attention core -> o_t[b][n][v] bf16.
// grid = 2048 (16 b * 128 qtiles of 32 q), 512 threads (8 waves), XCD-swizzled.
// pass1: S^T tiles via mfma(phi, Q) (C row=m, col=q) -> b64 LDS writes +
//        in-register row-max (shfl over lg). Wave owns m in [wv*128,+128).
// pass2: exp + sum, in-place repack to bf16 pairs.
// pass3: o[v][q] via mfma(g, P), wave owns v in [wv*32,+32), 2-step-deep
//        software pipeline on g/P fragment loads.
// ---------------------------------------------------------------------------
__global__ __launch_bounds__(512, 4) void k_attn2(
    const u16* __restrict__ theta, const u16* __restrict__ phi_t,
    const u16* __restrict__ g, u16* __restrict__ o_t)
{
  __shared__ __align__(16) u32 sc[32 * 516];   // 32 q rows x 1032 u16 (pad 8)
  __shared__ float pmax8[32][8];
  __shared__ float psum[32][16];
  __shared__ float sinv_s[32];

  const int tid  = threadIdx.x;
  const int lane = tid & 63;
  const int wv   = tid >> 6;       // wave id 0..7
  const int lg   = lane >> 4;      // lane-group 0..3 (k dimension)
  const int lr   = lane & 15;      // row/col within fragment
  const int bid  = blockIdx.x;
  const int swz  = ((bid & 7) << 8) | (bid >> 3);   // 2048 blocks, 8 XCDs
  const int b    = swz >> 7;
  const int bqt  = swz & 127;
  const int nq0  = bqt * 32;

  u16a* sc16 = (u16a*)sc;

  // ---- Q fragments as B operand: col=q (lr), k = kk*32+lg*8+i ----
  short8v qa[2][2];
#pragma unroll
  for (int qt = 0; qt < 2; ++qt)
#pragma unroll
    for (int kk = 0; kk < 2; ++kk) {
      Frag f;
#pragma unroll
      for (int i = 0; i < 8; ++i) {
        int d = kk * 32 + lg * 8 + i;
        f.u[i] = theta[((size_t)(b * DD + d)) * NPIX + nq0 + qt * 16 + lr];
      }
      qa[qt][kk] = f.s;
    }

  // ---- pass 1: S^T = phi^T theta (row=m, col=q); wave owns m [wv*128,+128) ----
  {
    float mx0 = -3.0e38f, mx1 = -3.0e38f;
    const u16* ptw = phi_t + ((size_t)(b * MM) + wv * 128 + lr) * DD + lg * 8;
    uint4 f0 = *(const uint4a*)(ptw);
    uint4 f1 = *(const uint4a*)(ptw + 32);
#pragma unroll
    for (int mt = 0; mt < 8; ++mt) {
      const int mtn = (mt < 7) ? mt + 1 : 7;
      uint4 n0v = *(const uint4a*)(ptw + (size_t)mtn * 16 * DD);
      uint4 n1v = *(const uint4a*)(ptw + (size_t)mtn * 16 * DD + 32);
      Frag a0; a0.q = f0; Frag a1; a1.q = f1;
      float4v s0 = {0.f, 0.f, 0.f, 0.f}, s1 = {0.f, 0.f, 0.f, 0.f};
      s0 = __builtin_amdgcn_mfma_f32_16x16x32_bf16(a0.s, qa[0][0], s0, 0, 0, 0);
      s0 = __builtin_amdgcn_mfma_f32_16x16x32_bf16(a1.s, qa[0][1], s0, 0, 0, 0);
      s1 = __builtin_amdgcn_mfma_f32_16x16x32_bf16(a0.s, qa[1][0], s1, 0, 0, 0);
      s1 = __builtin_amdgcn_mfma_f32_16x16x32_bf16(a1.s, qa[1][1], s1, 0, 0, 0);
      // clamp, pack fp16, b64 store: lane holds m = wv*128+mt*16+lg*4+r for q=lr
      float c0 = fminf(fmaxf(s0[0], -6.0e4f), 6.0e4f);
      float c1 = fminf(fmaxf(s0[1], -6.0e4f), 6.0e4f);
      float c2 = fminf(fmaxf(s0[2], -6.0e4f), 6.0e4f);
      float c3 = fminf(fmaxf(s0[3], -6.0e4f), 6.0e4f);
      mx0 = fmaxf(mx0, fmaxf(fmaxf(c0, c1), fmaxf(c2, c3)));
      uint2 w0;
      w0.x = (u32)f2h(c0) | ((u32)f2h(c1) << 16);
      w0.y = (u32)f2h(c2) | ((u32)f2h(c3) << 16);
      *(uint2a*)&sc16[(size_t)lr * 1032 + wv * 128 + mt * 16 + lg * 4] = w0;
      float d0 = fminf(fmaxf(s1[0], -6.0e4f), 6.0e4f);
      float d1 = fminf(fmaxf(s1[1], -6.0e4f), 6.0e4f);
      float d2 = fminf(fmaxf(s1[2], -6.0e4f), 6.0e4f);
      float d3 = fminf(fmaxf(s1[3], -6.0e4f), 6.0e4f);
      mx1 = fmaxf(mx1, fmaxf(fmaxf(d0, d1), fmaxf(d2, d3)));
      uint2 w1;
      w1.x = (u32)f2h(d0) | ((u32)f2h(d1) << 16);
      w1.y = (u32)f2h(d2) | ((u32)f2h(d3) << 16);
      *(uint2a*)&sc16[(size_t)(16 + lr) * 1032 + wv * 128 + mt * 16 + lg * 4] = w1;
      f0 = n0v; f1 = n1v;
    }
    // reduce max over lg (lanes differing in bits 4,5)
    mx0 = fmaxf(mx0, __shfl_xor(mx0, 16));
    mx0 = fmaxf(mx0, __shfl_xor(mx0, 32));
    mx1 = fmaxf(mx1, __shfl_xor(mx1, 16));
    mx1 = fmaxf(mx1, __shfl_xor(mx1, 32));
    if (lane < 16) {
      pmax8[lr][wv]      = mx0;
      pmax8[16 + lr][wv] = mx1;
    }
  }
  __syncthreads();

  // ---- pass 2: exp + sum; in-place repack to bf16 pairs ----
  const int q  = tid & 31;
  const int sg = tid >> 5;    // 16 segments x 64 m
  {
    float maxq = pmax8[q][0];
#pragma unroll
    for (int i = 1; i < 8; ++i) maxq = fmaxf(maxq, pmax8[q][i]);
    float ssum = 0.f;
#pragma unroll 4
    for (int kp = 0; kp < 32; ++kp) {
      int kk = (kp + sg) & 31;
      int idx = q * 516 + sg * 32 + kk;
      u32 raw = sc[idx];
      float f0 = h2f((u16)(raw & 0xffffu));
      float f1 = h2f((u16)(raw >> 16));
      float e0 = __expf(fminf(f0 - maxq, 0.f));
      float e1 = __expf(fminf(f1 - maxq, 0.f));
      ssum += e0 + e1;
      sc[idx] = (u32)f2b(e0) | ((u32)f2b(e1) << 16);
    }
    psum[q][sg] = ssum;
    __syncthreads();
    float tot = 0.f;
#pragma unroll
    for (int i = 0; i < 16; ++i) tot += psum[q][i];
    if (sg == 0) sinv_s[q] = 1.f / tot;
  }
  __syncthreads();

  // ---- pass 3: o[v][q] = sum_m g[v][m] P[q][m]; wave owns v [wv*32,+32) ----
  {
    const u16* gv0 = g + (size_t)b * (VV * MM) + ((size_t)(wv * 32) + lr) * MM + lg * 8;
    const u16* gv1 = gv0 + (size_t)16 * MM;
    const u16* p0b = sc16 + (size_t)lr * 1032 + lg * 8;
    const u16* p1b = p0b + (size_t)16 * 1032;

    float4v a00 = {0.f,0.f,0.f,0.f}, a01 = {0.f,0.f,0.f,0.f};
    float4v a10 = {0.f,0.f,0.f,0.f}, a11 = {0.f,0.f,0.f,0.f};

    uint4 ga0 = *(const uint4a*)(gv0);
    uint4 ga1 = *(const uint4a*)(gv1);
    uint4 pa0 = *(const uint4a*)(p0b);
    uint4 pa1 = *(const uint4a*)(p1b);
    uint4 gb0 = *(const uint4a*)(gv0 + 32);
    uint4 gb1 = *(const uint4a*)(gv1 + 32);
    uint4 pb0 = *(const uint4a*)(p0b + 32);
    uint4 pb1 = *(const uint4a*)(p1b + 32);

#pragma unroll 4
    for (int ms = 0; ms < 32; ms += 2) {
      const int m2 = (ms + 2 < 32) ? ms + 2 : 30;
      const int m3 = (ms + 3 < 32) ? ms + 3 : 31;
      uint4 gc0 = *(const uint4a*)(gv0 + m2 * 32);
      uint4 gc1 = *(const uint4a*)(gv1 + m2 * 32);
      uint4 pc0 = *(const uint4a*)(p0b + m2 * 32);
      uint4 pc1 = *(const uint4a*)(p1b + m2 * 32);
      {
        Frag x0, x1, y0, y1; x0.q = ga0; x1.q = ga1; y0.q = pa0; y1.q = pa1;
        a00 = __builtin_amdgcn_mfma_f32_16x16x32_bf16(x0.s, y0.s, a00, 0, 0, 0);
        a01 = __builtin_amdgcn_mfma_f32_16x16x32_bf16(x0.s, y1.s, a01, 0, 0, 0);
        a10 = __builtin_amdgcn_mfma_f32_16x16x32_bf16(x1.s, y0.s, a10, 0, 0, 0);
        a11 = __builtin_amdgcn_mfma_f32_16x16x32_bf16(x1.s, y1.s, a11, 0, 0, 0);
      }
      uint4 gd0 = *(const uint4a*)(gv0 + m3 * 32);
      uint4 gd1 = *(const uint4a*)(gv1 + m3 * 32);
      uint4 pd0 = *(const uint4a*)(p0b + m3 * 32);
      uint4 pd1 = *(const uint4a*)(p1b + m3 * 32);
      {
        Frag x0, x1, y0, y1; x0.q = gb0; x1.q = gb1; y0.q = pb0; y1.q = pb1;
        a00 = __builtin_amdgcn_mfma_f32_16x16x32_bf16(x0.s, y0.s, a00, 0, 0, 0);
        a01 = __builtin_amdgcn_mfma_f32_16x16x32_bf16(x0.s, y1.s, a01, 0, 0, 0);
        a10 = __builtin_amdgcn_mfma_f32_16x16x32_bf16(x1.s, y0.s, a10, 0, 0, 0);
        a11 = __builtin_amdgcn_mfma_f32_16x16x32_bf16(x1.s, y1.s, a11, 0, 0, 0);
      }
      ga0 = gc0; ga1 = gc1; pa0 = pc0; pa1 = pc1;
      gb0 = gd0; gb1 = gd1; pb0 = pd0; pb1 = pd1;
    }

    const float si0 = sinv_s[lr];
    const float si1 = sinv_s[16 + lr];
    // C layout: col=q (= qt*16+lr), row = v offset = lg*4+r within 16-v tile
    {
      uint2 wd;
      wd.x = cvtpk(a00[0] * si0, a00[1] * si0);
      wd.y = cvtpk(a00[2] * si0, a00[3] * si0);
      *(uint2a*)(o_t + ((size_t)(b * NPIX + nq0 + lr)) * VV + wv * 32 + lg * 4) = wd;
      wd.x = cvtpk(a01[0] * si1, a01[1] * si1);
      wd.y = cvtpk(a01[2] * si1, a01[3] * si1);
      *(uint2a*)(o_t + ((size_t)(b * NPIX + nq0 + 16 + lr)) * VV + wv * 32 + lg * 4) = wd;
      wd.x = cvtpk(a10[0] * si0, a10[1] * si0);
      wd.y = cvtpk(a10[2] * si0, a10[3] * si0);
      *(uint2a*)(o_t + ((size_t)(b * NPIX + nq0 + lr)) * VV + wv * 32 + 16 + lg * 4) = wd;
      wd.x = cvtpk(a11[0] * si1, a11[1] * si1);
      wd.y = cvtpk(a11[2] * si1, a11[3] * si1);
      *(uint2a*)(o_t + ((size_t)(b * NPIX + nq0 + 16 + lr)) * VV + wv * 32 + 16 + lg * 4) = wd;
    }
  }
}

// ---------------------------------------------------------------------------
// K2b (split path): out = gamma * (wo . o) + x.  GEMM over [512 oc][64 n]
// tiles, K = 256 v.  grid = 1024 (16 b * 64 ntiles), XCD-swizzled.
// ---------------------------------------------------------------------------
__global__ __launch_bounds__(256) void k_oproj(
    const u16* __restrict__ o_t, const u16* __restrict__ wo,
    const void* __restrict__ x, const float* __restrict__ gamma_p,
    const u32* __restrict__ meta, void* __restrict__ out)
{
  __shared__ __align__(16) u16 os[64][264];
  const int tid  = threadIdx.x;
  const int lane = tid & 63;
  const int wv   = tid >> 6;
  const int lg   = lane >> 4;
  const int lr   = lane & 15;
  const int bid  = blockIdx.x;
  const int swz  = ((bid & 7) << 7) | (bid >> 3);   // 1024 blocks, 8 XCDs
  const int b    = swz >> 6;
  const int nt   = swz & 63;
  const int n0   = nt * 64;
  const int flag = (int)meta[0];

  // stage o tile [64 n][256 v], coalesced uint4 rows
#pragma unroll
  for (int it = 0; it < 8; ++it) {
    int idx = tid + it * 256;
    int row = idx >> 5, cq = idx & 31;
    *(uint4a*)&os[row][cq * 8] =
        *(const uint4a*)(o_t + ((size_t)(b * NPIX + n0 + row)) * VV + cq * 8);
  }
  __syncthreads();

  float4v acc[8][4];
#pragma unroll
  for (int i = 0; i < 8; ++i)
#pragma unroll
    for (int j = 0; j < 4; ++j) acc[i][j] = (float4v){0.f, 0.f, 0.f, 0.f};

#pragma unroll
  for (int kk = 0; kk < 8; ++kk) {
    short8v bf4[4];
#pragma unroll
    for (int pt = 0; pt < 4; ++pt) {
      Frag f; f.q = *(const uint4a*)&os[pt * 16 + lr][kk * 32 + lg * 8];
      bf4[pt] = f.s;
    }
#pragma unroll
    for (int rt = 0; rt < 8; ++rt) {
      Frag af;
      af.q = *(const uint4a*)(wo + (size_t)(wv * 128 + rt * 16 + lr) * VV + kk * 32 + lg * 8);
#pragma unroll
      for (int pt = 0; pt < 4; ++pt)
        acc[rt][pt] = __builtin_amdgcn_mfma_f32_16x16x32_bf16(af.s, bf4[pt], acc[rt][pt], 0, 0, 0);
    }
  }

  const float gmv = gamma_p[0];
#pragma unroll
  for (int rt = 0; rt < 8; ++rt) {
#pragma unroll
    for (int pt = 0; pt < 4; ++pt) {
#pragma unroll
      for (int r = 0; r < 4; ++r) {
        int oc = wv * 128 + rt * 16 + lg * 4 + r;
        size_t off = ((size_t)(b * CIN + oc)) * NPIX + n0 + pt * 16 + lr;
        if (flag) {
          ((f32a*)out)[off] = gmv * acc[rt][pt][r] + ((const f32a*)x)[off];
        } else {
          ((u16a*)out)[off] = f2b(gmv * acc[rt][pt][r] + b2f(((const u16a*)x)[off]));
        }
      }
    }
  }
}

// ---------------------------------------------------------------------------
// K2 (fused fallback, used only if workspace can't hold o_t): unchanged.
// ---------------------------------------------------------------------------
__global__ __launch_bounds__(256) void k_attn(
    const u16* __restrict__ theta, const u16* __restrict__ phi_t,
    const u16* __restrict__ g, const u16* __restrict__ wo,
    const void* __restrict__ x, const float* __restrict__ gamma_p,
    const u32* __restrict__ meta, void* __restrict__ out)
{
  __shared__ __align__(16) u32 sc[16 * 516];
  __shared__ __align__(16) u16 ot[16 * 264];
  __shared__ float pmax[16][16];
  __shared__ float psum[16][16];
  __shared__ float sinv_s[16];

  const int tid  = threadIdx.x;
  const int lane = tid & 63;
  const int wv   = tid >> 6;
  const int lg   = lane >> 4;
  const int lr   = lane & 15;
  const int blk  = blockIdx.x;
  const int b    = blk >> 8;
  const int qt   = blk & 255;
  const int nq0  = qt * 16;
  const int flag = (int)meta[0];

  u16a* sc16 = (u16a*)sc;

  short8v qa[2];
#pragma unroll
  for (int kk = 0; kk < 2; ++kk) {
    Frag f;
#pragma unroll
    for (int i = 0; i < 8; ++i) {
      int d = kk * 32 + lg * 8 + i;
      f.u[i] = theta[((size_t)(b * DD + d)) * NPIX + nq0 + lr];
    }
    qa[kk] = f.s;
  }

  {
    const u16* pt = phi_t + (size_t)b * (MM * DD);
#pragma unroll 2
    for (int mt = 0; mt < 16; ++mt) {
      const int m0 = wv * 256 + mt * 16;
      float4v s = {0.f, 0.f, 0.f, 0.f};
#pragma unroll
      for (int kk = 0; kk < 2; ++kk) {
        Frag f; f.q = *(const uint4a*)(pt + (size_t)(m0 + lr) * DD + kk * 32 + lg * 8);
        s = __builtin_amdgcn_mfma_f32_16x16x32_bf16(qa[kk], f.s, s, 0, 0, 0);
      }
#pragma unroll
      for (int r = 0; r < 4; ++r) {
        int qq = lg * 4 + r;
        float v = fminf(fmaxf(s[r], -6.0e4f), 6.0e4f);
        sc16[qq * 1032 + m0 + lr] = f2h(v);
      }
    }
  }
  __syncthreads();

  {
    const int q  = tid & 15;
    const int sg = tid >> 4;
    float mx = -3.0e38f;
#pragma unroll 8
    for (int k = 0; k < 64; ++k) {
      int kk = (k + sg * 2) & 63;
      mx = fmaxf(mx, h2f(sc16[q * 1032 + sg * 64 + kk]));
    }
    pmax[q][sg] = mx;
    __syncthreads();
    float maxq = -3.0e38f;
#pragma unroll
    for (int i = 0; i < 16; ++i) maxq = fmaxf(maxq, pmax[q][i]);
    float ssum = 0.f;
#pragma unroll 4
    for (int kp = 0; kp < 32; ++kp) {
      int kk = (kp + sg) & 31;
      int idx = q * 516 + sg * 32 + kk;
      u32 raw = sc[idx];
      float f0 = h2f((u16)(raw & 0xffffu));
      float f1 = h2f((u16)(raw >> 16));
      float e0 = __expf(fminf(f0 - maxq, 0.f));
      float e1 = __expf(fminf(f1 - maxq, 0.f));
      ssum += e0 + e1;
      sc[idx] = (u32)f2b(e0) | ((u32)f2b(e1) << 16);
    }
    psum[q][sg] = ssum;
    __syncthreads();
    float tot = 0.f;
#pragma unroll
    for (int i = 0; i < 16; ++i) tot += psum[q][i];
    if (sg == 0) sinv_s[q] = 1.f / tot;
  }
  __syncthreads();

  const int q  = tid & 15;
  const int sg = tid >> 4;
  {
    float4v oacc[4];
#pragma unroll
    for (int i = 0; i < 4; ++i) oacc[i] = (float4v){0.f, 0.f, 0.f, 0.f};
    const u16* gb = g + (size_t)b * (VV * MM);
#pragma unroll 2
    for (int ms = 0; ms < 32; ++ms) {
      Frag pf; pf.q = *(const uint4a*)(sc16 + lr * 1032 + ms * 32 + lg * 8);
#pragma unroll
      for (int vt = 0; vt < 4; ++vt) {
        Frag gf; gf.q = *(const uint4a*)(gb + (size_t)(wv * 64 + vt * 16 + lr) * MM + ms * 32 + lg * 8);
        oacc[vt] = __builtin_amdgcn_mfma_f32_16x16x32_bf16(gf.s, pf.s, oacc[vt], 0, 0, 0);
      }
    }
    const float si = sinv_s[lr];
#pragma unroll
    for (int vt = 0; vt < 4; ++vt) {
      u32 lo = (u32)f2b(oacc[vt][0] * si) | ((u32)f2b(oacc[vt][1] * si) << 16);
      u32 hi = (u32)f2b(oacc[vt][2] * si) | ((u32)f2b(oacc[vt][3] * si) << 16);
      u32a* p = (u32a*)&ot[lr * 264 + wv * 64 + vt * 16 + lg * 4];
      p[0] = lo; p[1] = hi;
    }
  }
  __syncthreads();

  {
    short8v ob[8];
#pragma unroll
    for (int ks = 0; ks < 8; ++ks) {
      Frag f; f.q = *(const uint4a*)(ot + lr * 264 + ks * 32 + lg * 8);
      ob[ks] = f.s;
    }
    const float gmv = gamma_p[0];
    const int oc0 = wv * 128;
#pragma unroll 2
    for (int oct = 0; oct < 8; ++oct) {
      float4v c = {0.f, 0.f, 0.f, 0.f};
#pragma unroll
      for (int ks = 0; ks < 8; ++ks) {
        Frag f; f.q = *(const uint4a*)(wo + (size_t)(oc0 + oct * 16 + lr) * VV + ks * 32 + lg * 8);
        c = __builtin_amdgcn_mfma_f32_16x16x32_bf16(f.s, ob[ks], c, 0, 0, 0);
      }
#pragma unroll
      for (int r = 0; r < 4; ++r) {
        int oc = oc0 + oct * 16 + lg * 4 + r;
        size_t off = ((size_t)(b * CIN + oc)) * NPIX + nq0 + lr;
        if (flag) {
          ((f32a*)out)[off] = gmv * c[r] + ((const f32a*)x)[off];
        } else {
          ((u16a*)out)[off] = f2b(gmv * c[r] + b2f(((const u16a*)x)[off]));
        }
      }
    }
  }
}

extern "C" void kernel_launch(void* const* d_in, const int* in_sizes, int n_in,
                              void* d_out, int out_size, void* d_ws, size_t ws_size,
                              hipStream_t stream) {
  (void)in_sizes; (void)n_in; (void)out_size;
  const void* x  = d_in[0];
  const void* wt = d_in[1];
  const void* wp = d_in[2];
  const void* wg = d_in[3];
  const void* wo = d_in[4];
  const void* gm = d_in[5];

  u16* theta = (u16*)d_ws;                              // [16][64][4096]  bf16
  u16* phi_t = theta + (size_t)BATCH * DD * NPIX;       // [16][1024][64]  bf16
  u16* g     = phi_t + (size_t)BATCH * MM * DD;         // [16][256][1024] bf16
  u16* wbf   = g     + (size_t)BATCH * VV * MM;         // 327680 bf16 weights
  float* gamma_f = (float*)(wbf + 327680);              // converted gamma
  u32* meta      = (u32*)(gamma_f + 1);                 // dtype flag
  u16* o_t   = (u16*)d_ws + 9764896;                    // [16][4096][256] bf16 (split path)
  const size_t need = ((size_t)9764896 + (size_t)BATCH * NPIX * VV) * 2;

  hipLaunchKernelGGL(k_detect, dim3(1), dim3(256), 0, stream, x, meta);
  hipLaunchKernelGGL(k_cvt, dim3(1280), dim3(256), 0, stream,
                     wt, wp, wg, wo, gm, meta, wbf, gamma_f);
  hipLaunchKernelGGL(k_proj, dim3(BATCH * 32), dim3(256), 0, stream,
                     x, wbf, meta, theta, phi_t, g);
  if (ws_size >= need) {
    hipLaunchKernelGGL(k_attn2, dim3(BATCH * 128), dim3(512), 0, stream,
                       theta, phi_t, g, o_t);
    hipLaunchKernelGGL(k_oproj, dim3(BATCH * 64), dim3(256), 0, stream,
                       o_t, wbf + 196608, x, gamma_f, meta, d_out);
  } else {
    hipLaunchKernelGGL(k_attn, dim3(BATCH * 256), dim3(256), 0, stream,
                       theta, phi_t, g, wbf + 196608, x, gamma_f, meta, d_out);
  }
}

// Round 5
// 570.210 us; speedup vs baseline: 1.3515x; 1.1170x over previous
//
#include <hip/hip_runtime.h>
#include <hip/hip_fp16.h>

typedef unsigned int u32;
typedef unsigned short u16;
typedef u32 __attribute__((may_alias)) u32a;
typedef u16 __attribute__((may_alias)) u16a;
typedef uint4 __attribute__((may_alias)) uint4a;
typedef uint2 __attribute__((may_alias)) uint2a;
typedef float __attribute__((may_alias)) f32a;
typedef float4 __attribute__((may_alias)) float4a;

typedef __attribute__((ext_vector_type(8))) short short8v;  // 8 bf16 (4 VGPRs)
typedef __attribute__((ext_vector_type(4))) float float4v;  // 4 f32 acc

union Frag { uint4 q; short8v s; u16 u[8]; };
union F4 { float4 v; float f[4]; };

#define BATCH 16
#define CIN   512
#define NPIX  4096
#define DD    64
#define VV    256
#define MM    1024

__device__ __forceinline__ float b2f(u16 u) {
  union { u32 i; float f; } v; v.i = ((u32)u) << 16; return v.f;
}
__device__ __forceinline__ u16 f2b(float f) {
  union { float f; u32 i; } v; v.f = f;
  u32 u = v.i;
  u32 r = (u + 0x7fffu + ((u >> 16) & 1u)) >> 16;
  return (u16)r;
}
__device__ __forceinline__ u16 f2h(float f) { return __half_as_ushort(__float2half(f)); }
__device__ __forceinline__ float h2f(u16 u) { return __half2float(__ushort_as_half(u)); }

// packed RNE f32x2 -> bf16x2 (hardware cvt; same rounding as f2b)
__device__ __forceinline__ u32 cvtpk(float lo, float hi) {
  u32 r;
  asm("v_cvt_pk_bf16_f32 %0, %1, %2" : "=v"(r) : "v"(lo), "v"(hi));
  return r;
}

// packed bf16x2 dot product, f32 accumulate
__device__ __forceinline__ float dot2(u32 a, u32 b, float c) {
  union { u32 i; float f; } a0, a1, b0, b1;
  a0.i = a << 16; a1.i = a & 0xffff0000u;
  b0.i = b << 16; b1.i = b & 0xffff0000u;
  return fmaf(a1.f, b1.f, fmaf(a0.f, b0.f, c));
}

// ---------------------------------------------------------------------------
// K0a: input-dtype detection. meta[0] = 1 (inputs fp32) or 0 (inputs bf16).
// ---------------------------------------------------------------------------
__global__ __launch_bounds__(256) void k_detect(const void* __restrict__ x,
                                                u32* __restrict__ meta) {
  __shared__ int bad[256];
  const int t = threadIdx.x;
  float f = b2f(((const u16a*)x)[2 * t]);
  float a = fabsf(f);
  bad[t] = (a >= 1e-6f && a <= 100.f) ? 0 : 1;  // NaN -> bad (compares false)
  __syncthreads();
  if (t == 0) {
    int s = 0;
#pragma unroll 16
    for (int i = 0; i < 256; ++i) s += bad[i];
    meta[0] = (s > 64) ? 1u : 0u;
  }
}

// ---------------------------------------------------------------------------
// K0b: weights (+gamma) -> bf16 copy in ws.  wbf layout: wt@0, wp@32768,
// wg@65536, wo@196608 (u16 elements).  grid = 1280 x 256.
// ---------------------------------------------------------------------------
__global__ __launch_bounds__(256) void k_cvt(
    const void* __restrict__ wt, const void* __restrict__ wp,
    const void* __restrict__ wg, const void* __restrict__ wo,
    const void* __restrict__ gm, const u32* __restrict__ meta,
    u16* __restrict__ wbf, float* __restrict__ gout) {
  const int flag = (int)meta[0];
  const int i = blockIdx.x * 256 + threadIdx.x;
  const void* src; int j;
  if (i < 32768)       { src = wt; j = i; }
  else if (i < 65536)  { src = wp; j = i - 32768; }
  else if (i < 196608) { src = wg; j = i - 65536; }
  else                 { src = wo; j = i - 196608; }
  wbf[i] = flag ? f2b(((const f32a*)src)[j]) : ((const u16a*)src)[j];
  if (i == 0)
    gout[0] = flag ? ((const f32a*)gm)[0] : b2f(((const u16a*)gm)[0]);
}

// ---------------------------------------------------------------------------
// K1 (MFMA): theta/phi/g projections + fused 2x2 maxpool for phi,g.
// grid = 16 b * 32 pxt (128 px = 2 image rows each), 256 threads (4 waves).
// ---------------------------------------------------------------------------
__global__ __launch_bounds__(256) void k_proj(
    const void* __restrict__ x, const u16* __restrict__ w_all,
    const u32* __restrict__ meta,
    u16* __restrict__ theta, u16* __restrict__ phi_t, u16* __restrict__ g)
{
  __shared__ __align__(16) u16 xs[128][136];
  const int tid  = threadIdx.x;
  const int lane = tid & 63;
  const int wv   = tid >> 6;
  const int lg   = lane >> 4;      // k-group 0..3
  const int lr   = lane & 15;      // row/col within fragment
  const int blk  = blockIdx.x;
  const int b    = blk >> 5;
  const int pxt  = blk & 31;
  const int n0   = pxt * 128;      // 2 image rows y0=2*pxt, y0+1
  const int rbase = wv * 96;
  const int flag = (int)meta[0];

  float4v acc[6][8];
#pragma unroll
  for (int i = 0; i < 6; ++i)
#pragma unroll
    for (int j = 0; j < 8; ++j) acc[i][j] = (float4v){0.f, 0.f, 0.f, 0.f};

  const int pg = tid & 15;         // px quad: [pg*4, pg*4+4) and +64
  const int cg = tid >> 4;         // channel octet: [cg*8, cg*8+8)

  for (int cc = 0; cc < 4; ++cc) {
    const int c0 = cc * 128;
    __syncthreads();
    if (flag) {
      const f32a* src = (const f32a*)x +
          ((size_t)(b * CIN + c0 + cg * 8)) * NPIX + n0 + pg * 4;
#pragma unroll
      for (int cq = 0; cq < 2; ++cq) {        // two channel-quads
        const f32a* s4 = src + (size_t)(cq * 4) * NPIX;
        F4 a0, a1, a2, a3, b0, b1, b2, b3;
        a0.v = *(const float4a*)(s4);
        b0.v = *(const float4a*)(s4 + 64);
        a1.v = *(const float4a*)(s4 + NPIX);
        b1.v = *(const float4a*)(s4 + NPIX + 64);
        a2.v = *(const float4a*)(s4 + 2 * (size_t)NPIX);
        b2.v = *(const float4a*)(s4 + 2 * (size_t)NPIX + 64);
        a3.v = *(const float4a*)(s4 + 3 * (size_t)NPIX);
        b3.v = *(const float4a*)(s4 + 3 * (size_t)NPIX + 64);
        const int colb = cg * 8 + cq * 4;
#pragma unroll
        for (int j = 0; j < 4; ++j) {
          uint2 wd; wd.x = cvtpk(a0.f[j], a1.f[j]); wd.y = cvtpk(a2.f[j], a3.f[j]);
          *(uint2a*)&xs[pg * 4 + j][colb] = wd;
          uint2 vd; vd.x = cvtpk(b0.f[j], b1.f[j]); vd.y = cvtpk(b2.f[j], b3.f[j]);
          *(uint2a*)&xs[64 + pg * 4 + j][colb] = vd;
        }
      }
    } else {
#pragma unroll 8
      for (int it = 0; it < 64; ++it) {
        int idx = tid + it * 256;
        int cl = idx >> 7, px = idx & 127;
        xs[px][cl] = ((const u16a*)x)[((size_t)(b * CIN + c0 + cl)) * NPIX + (n0 + px)];
      }
    }
    __syncthreads();

#pragma unroll
    for (int kk = 0; kk < 4; ++kk) {
      short8v bfr[8];
#pragma unroll
      for (int pt = 0; pt < 8; ++pt) {
        Frag f; f.q = *(const uint4a*)&xs[pt * 16 + lr][kk * 32 + lg * 8];
        bfr[pt] = f.s;
      }
#pragma unroll
      for (int rt = 0; rt < 6; ++rt) {
        Frag af;
        af.q = *(const uint4a*)(w_all +
            (size_t)(rbase + rt * 16 + lr) * CIN + c0 + kk * 32 + lg * 8);
#pragma unroll
        for (int pt = 0; pt < 8; ++pt)
          acc[rt][pt] = __builtin_amdgcn_mfma_f32_16x16x32_bf16(af.s, bfr[pt], acc[rt][pt], 0, 0, 0);
      }
    }
  }

#pragma unroll
  for (int rt = 0; rt < 6; ++rt) {
    const int rowb = rbase + rt * 16;
    if (rowb < 64) {
#pragma unroll
      for (int pt = 0; pt < 8; ++pt)
#pragma unroll
        for (int r = 0; r < 4; ++r) {
          int row = rowb + lg * 4 + r;
          theta[((size_t)(b * DD + row)) * NPIX + n0 + pt * 16 + lr] = f2b(acc[rt][pt][r]);
        }
    } else {
#pragma unroll
      for (int pt = 0; pt < 4; ++pt)
#pragma unroll
        for (int r = 0; r < 4; ++r) {
          int row = rowb + lg * 4 + r;
          float pm = fmaxf(acc[rt][pt][r], acc[rt][pt + 4][r]);
          float po = fmaxf(pm, __shfl_xor(pm, 1));
          if (!(lr & 1)) {
            int m = pxt * 32 + pt * 8 + (lr >> 1);
            if (row < 128) phi_t[((size_t)(b * MM + m)) * DD + (row - 64)] = f2b(po);
            else           g[((size_t)(b * VV + (row - 128))) * MM + m]    = f2b(po);
          }
        }
    }
  }
}

// ---------------------------------------------------------------------------
// K2a (split path, QBLK=32): attention core -> o_t[b][n][v] bf16.
// grid = 2048 (16 b * 128 qtiles of 32 q), 512 threads (8 waves), XCD-swizzled.
// ---------------------------------------------------------------------------
__global__ __launch_bounds__(512, 4) void k_attn2(
    const u16* __restrict__ theta, const u16* __restrict__ phi_t,
    const u16* __restrict__ g, u16* __restrict__ o_t)
{
  __shared__ __align__(16) u32 sc[32 * 516];   // 32 q rows x 1032 u16 (pad 8)
  __shared__ float pmax8[32][8];
  __shared__ float psum[32][16];
  __shared__ float sinv_s[32];

  const int tid  = threadIdx.x;
  const int lane = tid & 63;
  const int wv   = tid >> 6;       // wave id 0..7
  const int lg   = lane >> 4;      // lane-group 0..3 (k dimension)
  const int lr   = lane & 15;      // row/col within fragment
  const int bid  = blockIdx.x;
  const int swz  = ((bid & 7) << 8) | (bid >> 3);   // 2048 blocks, 8 XCDs
  const int b    = swz >> 7;
  const int bqt  = swz & 127;
  const int nq0  = bqt * 32;

  u16a* sc16 = (u16a*)sc;

  // ---- Q fragments as B operand: col=q (lr), k = kk*32+lg*8+i ----
  short8v qa[2][2];
#pragma unroll
  for (int qt = 0; qt < 2; ++qt)
#pragma unroll
    for (int kk = 0; kk < 2; ++kk) {
      Frag f;
#pragma unroll
      for (int i = 0; i < 8; ++i) {
        int d = kk * 32 + lg * 8 + i;
        f.u[i] = theta[((size_t)(b * DD + d)) * NPIX + nq0 + qt * 16 + lr];
      }
      qa[qt][kk] = f.s;
    }

  // ---- pass 1: S^T = phi^T theta (row=m, col=q); wave owns m [wv*128,+128) ----
  {
    float mx0 = -3.0e38f, mx1 = -3.0e38f;
    const u16* ptw = phi_t + ((size_t)(b * MM) + wv * 128 + lr) * DD + lg * 8;
    uint4 f0 = *(const uint4a*)(ptw);
    uint4 f1 = *(const uint4a*)(ptw + 32);
#pragma unroll
    for (int mt = 0; mt < 8; ++mt) {
      const int mtn = (mt < 7) ? mt + 1 : 7;
      uint4 n0v = *(const uint4a*)(ptw + (size_t)mtn * 16 * DD);
      uint4 n1v = *(const uint4a*)(ptw + (size_t)mtn * 16 * DD + 32);
      Frag a0; a0.q = f0; Frag a1; a1.q = f1;
      float4v s0 = {0.f, 0.f, 0.f, 0.f}, s1 = {0.f, 0.f, 0.f, 0.f};
      s0 = __builtin_amdgcn_mfma_f32_16x16x32_bf16(a0.s, qa[0][0], s0, 0, 0, 0);
      s0 = __builtin_amdgcn_mfma_f32_16x16x32_bf16(a1.s, qa[0][1], s0, 0, 0, 0);
      s1 = __builtin_amdgcn_mfma_f32_16x16x32_bf16(a0.s, qa[1][0], s1, 0, 0, 0);
      s1 = __builtin_amdgcn_mfma_f32_16x16x32_bf16(a1.s, qa[1][1], s1, 0, 0, 0);
      float c0 = fminf(fmaxf(s0[0], -6.0e4f), 6.0e4f);
      float c1 = fminf(fmaxf(s0[1], -6.0e4f), 6.0e4f);
      float c2 = fminf(fmaxf(s0[2], -6.0e4f), 6.0e4f);
      float c3 = fminf(fmaxf(s0[3], -6.0e4f), 6.0e4f);
      mx0 = fmaxf(mx0, fmaxf(fmaxf(c0, c1), fmaxf(c2, c3)));
      uint2 w0;
      w0.x = (u32)f2h(c0) | ((u32)f2h(c1) << 16);
      w0.y = (u32)f2h(c2) | ((u32)f2h(c3) << 16);
      *(uint2a*)&sc16[(size_t)lr * 1032 + wv * 128 + mt * 16 + lg * 4] = w0;
      float d0 = fminf(fmaxf(s1[0], -6.0e4f), 6.0e4f);
      float d1 = fminf(fmaxf(s1[1], -6.0e4f), 6.0e4f);
      float d2 = fminf(fmaxf(s1[2], -6.0e4f), 6.0e4f);
      float d3 = fminf(fmaxf(s1[3], -6.0e4f), 6.0e4f);
      mx1 = fmaxf(mx1, fmaxf(fmaxf(d0, d1), fmaxf(d2, d3)));
      uint2 w1;
      w1.x = (u32)f2h(d0) | ((u32)f2h(d1) << 16);
      w1.y = (u32)f2h(d2) | ((u32)f2h(d3) << 16);
      *(uint2a*)&sc16[(size_t)(16 + lr) * 1032 + wv * 128 + mt * 16 + lg * 4] = w1;
      f0 = n0v; f1 = n1v;
    }
    mx0 = fmaxf(mx0, __shfl_xor(mx0, 16));
    mx0 = fmaxf(mx0, __shfl_xor(mx0, 32));
    mx1 = fmaxf(mx1, __shfl_xor(mx1, 16));
    mx1 = fmaxf(mx1, __shfl_xor(mx1, 32));
    if (lane < 16) {
      pmax8[lr][wv]      = mx0;
      pmax8[16 + lr][wv] = mx1;
    }
  }
  __syncthreads();

  // ---- pass 2: exp + sum; in-place repack to bf16 pairs ----
  const int q  = tid & 31;
  const int sg = tid >> 5;    // 16 segments x 64 m
  {
    float maxq = pmax8[q][0];
#pragma unroll
    for (int i = 1; i < 8; ++i) maxq = fmaxf(maxq, pmax8[q][i]);
    float ssum = 0.f;
#pragma unroll 4
    for (int kp = 0; kp < 32; ++kp) {
      int kk = (kp + sg) & 31;
      int idx = q * 516 + sg * 32 + kk;
      u32 raw = sc[idx];
      float f0 = h2f((u16)(raw & 0xffffu));
      float f1 = h2f((u16)(raw >> 16));
      float e0 = __expf(fminf(f0 - maxq, 0.f));
      float e1 = __expf(fminf(f1 - maxq, 0.f));
      ssum += e0 + e1;
      sc[idx] = (u32)f2b(e0) | ((u32)f2b(e1) << 16);
    }
    psum[q][sg] = ssum;
    __syncthreads();
    float tot = 0.f;
#pragma unroll
    for (int i = 0; i < 16; ++i) tot += psum[q][i];
    if (sg == 0) sinv_s[q] = 1.f / tot;
  }
  __syncthreads();

  // ---- pass 3: o[v][q] = sum_m g[v][m] P[q][m]; wave owns v [wv*32,+32) ----
  {
    const u16* gv0 = g + (size_t)b * (VV * MM) + ((size_t)(wv * 32) + lr) * MM + lg * 8;
    const u16* gv1 = gv0 + (size_t)16 * MM;
    const u16* p0b = sc16 + (size_t)lr * 1032 + lg * 8;
    const u16* p1b = p0b + (size_t)16 * 1032;

    float4v a00 = {0.f,0.f,0.f,0.f}, a01 = {0.f,0.f,0.f,0.f};
    float4v a10 = {0.f,0.f,0.f,0.f}, a11 = {0.f,0.f,0.f,0.f};

    uint4 ga0 = *(const uint4a*)(gv0);
    uint4 ga1 = *(const uint4a*)(gv1);
    uint4 pa0 = *(const uint4a*)(p0b);
    uint4 pa1 = *(const uint4a*)(p1b);
    uint4 gb0 = *(const uint4a*)(gv0 + 32);
    uint4 gb1 = *(const uint4a*)(gv1 + 32);
    uint4 pb0 = *(const uint4a*)(p0b + 32);
    uint4 pb1 = *(const uint4a*)(p1b + 32);

#pragma unroll 4
    for (int ms = 0; ms < 32; ms += 2) {
      const int m2 = (ms + 2 < 32) ? ms + 2 : 30;
      const int m3 = (ms + 3 < 32) ? ms + 3 : 31;
      uint4 gc0 = *(const uint4a*)(gv0 + m2 * 32);
      uint4 gc1 = *(const uint4a*)(gv1 + m2 * 32);
      uint4 pc0 = *(const uint4a*)(p0b + m2 * 32);
      uint4 pc1 = *(const uint4a*)(p1b + m2 * 32);
      {
        Frag x0, x1, y0, y1; x0.q = ga0; x1.q = ga1; y0.q = pa0; y1.q = pa1;
        a00 = __builtin_amdgcn_mfma_f32_16x16x32_bf16(x0.s, y0.s, a00, 0, 0, 0);
        a01 = __builtin_amdgcn_mfma_f32_16x16x32_bf16(x0.s, y1.s, a01, 0, 0, 0);
        a10 = __builtin_amdgcn_mfma_f32_16x16x32_bf16(x1.s, y0.s, a10, 0, 0, 0);
        a11 = __builtin_amdgcn_mfma_f32_16x16x32_bf16(x1.s, y1.s, a11, 0, 0, 0);
      }
      uint4 gd0 = *(const uint4a*)(gv0 + m3 * 32);
      uint4 gd1 = *(const uint4a*)(gv1 + m3 * 32);
      uint4 pd0 = *(const uint4a*)(p0b + m3 * 32);
      uint4 pd1 = *(const uint4a*)(p1b + m3 * 32);
      {
        Frag x0, x1, y0, y1; x0.q = gb0; x1.q = gb1; y0.q = pb0; y1.q = pb1;
        a00 = __builtin_amdgcn_mfma_f32_16x16x32_bf16(x0.s, y0.s, a00, 0, 0, 0);
        a01 = __builtin_amdgcn_mfma_f32_16x16x32_bf16(x0.s, y1.s, a01, 0, 0, 0);
        a10 = __builtin_amdgcn_mfma_f32_16x16x32_bf16(x1.s, y0.s, a10, 0, 0, 0);
        a11 = __builtin_amdgcn_mfma_f32_16x16x32_bf16(x1.s, y1.s, a11, 0, 0, 0);
      }
      ga0 = gc0; ga1 = gc1; pa0 = pc0; pa1 = pc1;
      gb0 = gd0; gb1 = gd1; pb0 = pd0; pb1 = pd1;
    }

    const float si0 = sinv_s[lr];
    const float si1 = sinv_s[16 + lr];
    {
      uint2 wd;
      wd.x = cvtpk(a00[0] * si0, a00[1] * si0);
      wd.y = cvtpk(a00[2] * si0, a00[3] * si0);
      *(uint2a*)(o_t + ((size_t)(b * NPIX + nq0 + lr)) * VV + wv * 32 + lg * 4) = wd;
      wd.x = cvtpk(a01[0] * si1, a01[1] * si1);
      wd.y = cvtpk(a01[2] * si1, a01[3] * si1);
      *(uint2a*)(o_t + ((size_t)(b * NPIX + nq0 + 16 + lr)) * VV + wv * 32 + lg * 4) = wd;
      wd.x = cvtpk(a10[0] * si0, a10[1] * si0);
      wd.y = cvtpk(a10[2] * si0, a10[3] * si0);
      *(uint2a*)(o_t + ((size_t)(b * NPIX + nq0 + lr)) * VV + wv * 32 + 16 + lg * 4) = wd;
      wd.x = cvtpk(a11[0] * si1, a11[1] * si1);
      wd.y = cvtpk(a11[2] * si1, a11[3] * si1);
      *(uint2a*)(o_t + ((size_t)(b * NPIX + nq0 + 16 + lr)) * VV + wv * 32 + 16 + lg * 4) = wd;
    }
  }
}

// ---------------------------------------------------------------------------
// K2b v2: out = gamma * (wo . o) + x, operand-swapped MFMA (C row=n, col=oc)
// so the epilogue is float4-vectorized along n.  No LDS, no barriers:
// A-frags (o_t, row=n, v-contig) and B-frags (wo, row=oc, v-contig) are
// loaded straight from global (wo is L2-hot, o_t rows L2-shared by och pair).
// grid = 4096 (16 b * 128 nt * 2 och), 256 thr, XCD-swizzled (b-major).
// Per wave: 64 oc x 32 n -> acc[4][2] (32 VGPR).
// ---------------------------------------------------------------------------
__global__ __launch_bounds__(256, 4) void k_oproj(
    const u16* __restrict__ o_t, const u16* __restrict__ wo,
    const void* __restrict__ x, const float* __restrict__ gamma_p,
    const u32* __restrict__ meta, void* __restrict__ out)
{
  const int tid  = threadIdx.x;
  const int lane = tid & 63;
  const int wv   = tid >> 6;       // 0..3
  const int lg   = lane >> 4;
  const int lr   = lane & 15;
  const int bid  = blockIdx.x;
  const int swz  = ((bid & 7) << 9) | (bid >> 3);   // 4096 blocks, 8 XCDs
  const int b    = swz >> 8;
  const int nt   = (swz >> 1) & 127;
  const int och  = swz & 1;
  const int n0   = nt * 32;
  const int ocb  = och * 256 + wv * 64;
  const int flag = (int)meta[0];

  float4v acc[4][2];
#pragma unroll
  for (int j = 0; j < 4; ++j)
#pragma unroll
    for (int t = 0; t < 2; ++t) acc[j][t] = (float4v){0.f, 0.f, 0.f, 0.f};

  const u16* obl = o_t + ((size_t)(b * NPIX) + n0 + lr) * VV;  // A: n = n0[+16]+lr
  const u16* wbl = wo + (size_t)(ocb + lr) * VV;               // B: oc = ocb+j*16+lr

#pragma unroll 2
  for (int kk = 0; kk < 8; ++kk) {
    const int ko = kk * 32 + lg * 8;
    Frag a0, a1, w0, w1, w2, w3;
    a0.q = *(const uint4a*)(obl + ko);
    a1.q = *(const uint4a*)(obl + (size_t)16 * VV + ko);
    w0.q = *(const uint4a*)(wbl + ko);
    w1.q = *(const uint4a*)(wbl + (size_t)16 * VV + ko);
    w2.q = *(const uint4a*)(wbl + (size_t)32 * VV + ko);
    w3.q = *(const uint4a*)(wbl + (size_t)48 * VV + ko);
    acc[0][0] = __builtin_amdgcn_mfma_f32_16x16x32_bf16(a0.s, w0.s, acc[0][0], 0, 0, 0);
    acc[0][1] = __builtin_amdgcn_mfma_f32_16x16x32_bf16(a1.s, w0.s, acc[0][1], 0, 0, 0);
    acc[1][0] = __builtin_amdgcn_mfma_f32_16x16x32_bf16(a0.s, w1.s, acc[1][0], 0, 0, 0);
    acc[1][1] = __builtin_amdgcn_mfma_f32_16x16x32_bf16(a1.s, w1.s, acc[1][1], 0, 0, 0);
    acc[2][0] = __builtin_amdgcn_mfma_f32_16x16x32_bf16(a0.s, w2.s, acc[2][0], 0, 0, 0);
    acc[2][1] = __builtin_amdgcn_mfma_f32_16x16x32_bf16(a1.s, w2.s, acc[2][1], 0, 0, 0);
    acc[3][0] = __builtin_amdgcn_mfma_f32_16x16x32_bf16(a0.s, w3.s, acc[3][0], 0, 0, 0);
    acc[3][1] = __builtin_amdgcn_mfma_f32_16x16x32_bf16(a1.s, w3.s, acc[3][1], 0, 0, 0);
  }

  // epilogue: C col = oc = ocb + j*16 + lr; rows = 4 consecutive n
  // n = n0 + t*16 + lg*4 + r  ->  float4 x-load / out-store per fragment.
  const float gmv = gamma_p[0];
#pragma unroll
  for (int j = 0; j < 4; ++j) {
    const int oc = ocb + j * 16 + lr;
#pragma unroll
    for (int t = 0; t < 2; ++t) {
      const size_t off = ((size_t)(b * CIN + oc)) * NPIX + n0 + t * 16 + lg * 4;
      if (flag) {
        F4 xv; xv.v = *(const float4a*)((const f32a*)x + off);
        F4 o;
        o.f[0] = gmv * acc[j][t][0] + xv.f[0];
        o.f[1] = gmv * acc[j][t][1] + xv.f[1];
        o.f[2] = gmv * acc[j][t][2] + xv.f[2];
        o.f[3] = gmv * acc[j][t][3] + xv.f[3];
        *(float4a*)((f32a*)out + off) = o.v;
      } else {
        uint2 xv = *(const uint2a*)((const u16a*)x + off);
        uint2 st;
        st.x = (u32)f2b(gmv * acc[j][t][0] + b2f((u16)(xv.x & 0xffffu))) |
               ((u32)f2b(gmv * acc[j][t][1] + b2f((u16)(xv.x >> 16))) << 16);
        st.y = (u32)f2b(gmv * acc[j][t][2] + b2f((u16)(xv.y & 0xffffu))) |
               ((u32)f2b(gmv * acc[j][t][3] + b2f((u16)(xv.y >> 16))) << 16);
        *(uint2a*)((u16a*)out + off) = st;
      }
    }
  }
}

// ---------------------------------------------------------------------------
// K2 (fused fallback, used only if workspace can't hold o_t): unchanged.
// ---------------------------------------------------------------------------
__global__ __launch_bounds__(256) void k_attn(
    const u16* __restrict__ theta, const u16* __restrict__ phi_t,
    const u16* __restrict__ g, const u16* __restrict__ wo,
    const void* __restrict__ x, const float* __restrict__ gamma_p,
    const u32* __restrict__ meta, void* __restrict__ out)
{
  __shared__ __align__(16) u32 sc[16 * 516];
  __shared__ __align__(16) u16 ot[16 * 264];
  __shared__ float pmax[16][16];
  __shared__ float psum[16][16];
  __shared__ float sinv_s[16];

  const int tid  = threadIdx.x;
  const int lane = tid & 63;
  const int wv   = tid >> 6;
  const int lg   = lane >> 4;
  const int lr   = lane & 15;
  const int blk  = blockIdx.x;
  const int b    = blk >> 8;
  const int qt   = blk & 255;
  const int nq0  = qt * 16;
  const int flag = (int)meta[0];

  u16a* sc16 = (u16a*)sc;

  short8v qa[2];
#pragma unroll
  for (int kk = 0; kk < 2; ++kk) {
    Frag f;
#pragma unroll
    for (int i = 0; i < 8; ++i) {
      int d = kk * 32 + lg * 8 + i;
      f.u[i] = theta[((size_t)(b * DD + d)) * NPIX + nq0 + lr];
    }
    qa[kk] = f.s;
  }

  {
    const u16* pt = phi_t + (size_t)b * (MM * DD);
#pragma unroll 2
    for (int mt = 0; mt < 16; ++mt) {
      const int m0 = wv * 256 + mt * 16;
      float4v s = {0.f, 0.f, 0.f, 0.f};
#pragma unroll
      for (int kk = 0; kk < 2; ++kk) {
        Frag f; f.q = *(const uint4a*)(pt + (size_t)(m0 + lr) * DD + kk * 32 + lg * 8);
        s = __builtin_amdgcn_mfma_f32_16x16x32_bf16(qa[kk], f.s, s, 0, 0, 0);
      }
#pragma unroll
      for (int r = 0; r < 4; ++r) {
        int qq = lg * 4 + r;
        float v = fminf(fmaxf(s[r], -6.0e4f), 6.0e4f);
        sc16[qq * 1032 + m0 + lr] = f2h(v);
      }
    }
  }
  __syncthreads();

  {
    const int q  = tid & 15;
    const int sg = tid >> 4;
    float mx = -3.0e38f;
#pragma unroll 8
    for (int k = 0; k < 64; ++k) {
      int kk = (k + sg * 2) & 63;
      mx = fmaxf(mx, h2f(sc16[q * 1032 + sg * 64 + kk]));
    }
    pmax[q][sg] = mx;
    __syncthreads();
    float maxq = -3.0e38f;
#pragma unroll
    for (int i = 0; i < 16; ++i) maxq = fmaxf(maxq, pmax[q][i]);
    float ssum = 0.f;
#pragma unroll 4
    for (int kp = 0; kp < 32; ++kp) {
      int kk = (kp + sg) & 31;
      int idx = q * 516 + sg * 32 + kk;
      u32 raw = sc[idx];
      float f0 = h2f((u16)(raw & 0xffffu));
      float f1 = h2f((u16)(raw >> 16));
      float e0 = __expf(fminf(f0 - maxq, 0.f));
      float e1 = __expf(fminf(f1 - maxq, 0.f));
      ssum += e0 + e1;
      sc[idx] = (u32)f2b(e0) | ((u32)f2b(e1) << 16);
    }
    psum[q][sg] = ssum;
    __syncthreads();
    float tot = 0.f;
#pragma unroll
    for (int i = 0; i < 16; ++i) tot += psum[q][i];
    if (sg == 0) sinv_s[q] = 1.f / tot;
  }
  __syncthreads();

  const int q  = tid & 15;
  const int sg = tid >> 4;
  {
    float4v oacc[4];
#pragma unroll
    for (int i = 0; i < 4; ++i) oacc[i] = (float4v){0.f, 0.f, 0.f, 0.f};
    const u16* gb = g + (size_t)b * (VV * MM);
#pragma unroll 2
    for (int ms = 0; ms < 32; ++ms) {
      Frag pf; pf.q = *(const uint4a*)(sc16 + lr * 1032 + ms * 32 + lg * 8);
#pragma unroll
      for (int vt = 0; vt < 4; ++vt) {
        Frag gf; gf.q = *(const uint4a*)(gb + (size_t)(wv * 64 + vt * 16 + lr) * MM + ms * 32 + lg * 8);
        oacc[vt] = __builtin_amdgcn_mfma_f32_16x16x32_bf16(gf.s, pf.s, oacc[vt], 0, 0, 0);
      }
    }
    const float si = sinv_s[lr];
#pragma unroll
    for (int vt = 0; vt < 4; ++vt) {
      u32 lo = (u32)f2b(oacc[vt][0] * si) | ((u32)f2b(oacc[vt][1] * si) << 16);
      u32 hi = (u32)f2b(oacc[vt][2] * si) | ((u32)f2b(oacc[vt][3] * si) << 16);
      u32a* p = (u32a*)&ot[lr * 264 + wv * 64 + vt * 16 + lg * 4];
      p[0] = lo; p[1] = hi;
    }
  }
  __syncthreads();

  {
    short8v ob[8];
#pragma unroll
    for (int ks = 0; ks < 8; ++ks) {
      Frag f; f.q = *(const uint4a*)(ot + lr * 264 + ks * 32 + lg * 8);
      ob[ks] = f.s;
    }
    const float gmv = gamma_p[0];
    const int oc0 = wv * 128;
#pragma unroll 2
    for (int oct = 0; oct < 8; ++oct) {
      float4v c = {0.f, 0.f, 0.f, 0.f};
#pragma unroll
      for (int ks = 0; ks < 8; ++ks) {
        Frag f; f.q = *(const uint4a*)(wo + (size_t)(oc0 + oct * 16 + lr) * VV + ks * 32 + lg * 8);
        c = __builtin_amdgcn_mfma_f32_16x16x32_bf16(f.s, ob[ks], c, 0, 0, 0);
      }
#pragma unroll
      for (int r = 0; r < 4; ++r) {
        int oc = oc0 + oct * 16 + lg * 4 + r;
        size_t off = ((size_t)(b * CIN + oc)) * NPIX + nq0 + lr;
        if (flag) {
          ((f32a*)out)[off] = gmv * c[r] + ((const f32a*)x)[off];
        } else {
          ((u16a*)out)[off] = f2b(gmv * c[r] + b2f(((const u16a*)x)[off]));
        }
      }
    }
  }
}

extern "C" void kernel_launch(void* const* d_in, const int* in_sizes, int n_in,
                              void* d_out, int out_size, void* d_ws, size_t ws_size,
                              hipStream_t stream) {
  (void)in_sizes; (void)n_in; (void)out_size;
  const void* x  = d_in[0];
  const void* wt = d_in[1];
  const void* wp = d_in[2];
  const void* wg = d_in[3];
  const void* wo = d_in[4];
  const void* gm = d_in[5];

  u16* theta = (u16*)d_ws;                              // [16][64][4096]  bf16
  u16* phi_t = theta + (size_t)BATCH * DD * NPIX;       // [16][1024][64]  bf16
  u16* g     = phi_t + (size_t)BATCH * MM * DD;         // [16][256][1024] bf16
  u16* wbf   = g     + (size_t)BATCH * VV * MM;         // 327680 bf16 weights
  float* gamma_f = (float*)(wbf + 327680);              // converted gamma
  u32* meta      = (u32*)(gamma_f + 1);                 // dtype flag
  u16* o_t   = (u16*)d_ws + 9764896;                    // [16][4096][256] bf16 (split path)
  const size_t need = ((size_t)9764896 + (size_t)BATCH * NPIX * VV) * 2;

  hipLaunchKernelGGL(k_detect, dim3(1), dim3(256), 0, stream, x, meta);
  hipLaunchKernelGGL(k_cvt, dim3(1280), dim3(256), 0, stream,
                     wt, wp, wg, wo, gm, meta, wbf, gamma_f);
  hipLaunchKernelGGL(k_proj, dim3(BATCH * 32), dim3(256), 0, stream,
                     x, wbf, meta, theta, phi_t, g);
  if (ws_size >= need) {
    hipLaunchKernelGGL(k_attn2, dim3(BATCH * 128), dim3(512), 0, stream,
                       theta, phi_t, g, o_t);
    hipLaunchKernelGGL(k_oproj, dim3(BATCH * 256), dim3(256), 0, stream,
                       o_t, wbf + 196608, x, gamma_f, meta, d_out);
  } else {
    hipLaunchKernelGGL(k_attn, dim3(BATCH * 256), dim3(256), 0, stream,
                       theta, phi_t, g, wbf + 196608, x, gamma_f, meta, d_out);
  }
}